// Round 4
// baseline (476.823 us; speedup 1.0000x reference)
//
#include <hip/hip_runtime.h>
#include <hip/hip_bf16.h>
#include <hip/hip_fp16.h>

typedef __attribute__((ext_vector_type(8))) short short8;
typedef __attribute__((ext_vector_type(4))) float f32x4;
typedef __attribute__((ext_vector_type(4))) unsigned int u32x4;
typedef __attribute__((ext_vector_type(2))) unsigned int u32x2;
typedef __attribute__((ext_vector_type(4))) int i32x4;
typedef __attribute__((ext_vector_type(2))) int i32x2;

// ---------------- bf16 helpers ----------------
__device__ __forceinline__ float bflo(unsigned int u) { return __uint_as_float(u << 16); }
__device__ __forceinline__ float bfhi(unsigned int u) { return __uint_as_float(u & 0xffff0000u); }
__device__ __forceinline__ unsigned int bfrne(float f) {
    unsigned int u = __float_as_uint(f);
    return (u + 0x7fffu + ((u >> 16) & 1u)) >> 16;
}
__device__ __forceinline__ unsigned int packbf2(float lo, float hi) {
    return (bfrne(lo) & 0xffffu) | (bfrne(hi) << 16);
}
__device__ __forceinline__ short8 pack8(const float* f) {
    short8 r;
#pragma unroll
    for (int i = 0; i < 8; i += 2) {
        unsigned int p = packbf2(f[i], f[i + 1]);
        r[i] = (short)(p & 0xffffu);
        r[i + 1] = (short)(p >> 16);
    }
    return r;
}

// ---------------- f16 helpers ----------------
__device__ __forceinline__ unsigned int packh2(float lo, float hi) {
    unsigned int a = __half_as_ushort(__float2half_rn(lo));
    unsigned int b = __half_as_ushort(__float2half_rn(hi));
    return a | (b << 16);
}
__device__ __forceinline__ void unpackh8(u32x4 v, float* f) {
#pragma unroll
    for (int j = 0; j < 4; ++j) {
        f[2 * j]     = __half2float(__ushort_as_half((unsigned short)(v[j] & 0xffffu)));
        f[2 * j + 1] = __half2float(__ushort_as_half((unsigned short)(v[j] >> 16)));
    }
}

// ---------------- fast math ----------------
__device__ __forceinline__ float fast_rcp(float x) { return __builtin_amdgcn_rcpf(x); }
__device__ __forceinline__ float sigmoidf_fast(float x) { return fast_rcp(1.0f + __expf(-x)); }
__device__ __forceinline__ float tanhf_fast(float x) {
    float e = __expf(2.0f * x);
    return 1.0f - 2.0f * fast_rcp(e + 1.0f);
}

// ---------------------------------------------------------------------------
// Prep (grid ~293 blocks):
//   * every block sniffs dtypes from the head of emb/edges (cheap, L2-shared):
//     flags[0]=1 iff emb is f32-backed; i64-ness detected locally.
//   * blocks 0-2 pack the three 128x128 W matrices to bf16 (block 0 publishes
//     flags for the downstream kernels; same-stream ordering).
//   * all blocks convert their 2048-edge slice to packed int32 (a,b) pairs in
//     Ep: edge_kernel then has no dtype branch and reads 4.8MB instead of 9.6.
// ---------------------------------------------------------------------------
__global__ __launch_bounds__(256)
void prep_kernel(const void* __restrict__ w0v, const void* __restrict__ w1v,
                 const void* __restrict__ w2v,
                 unsigned short* __restrict__ Wb,
                 const unsigned short* __restrict__ emb16,
                 const int* __restrict__ e32,
                 int* __restrict__ Ep,
                 int* __restrict__ flags, int n_edges)
{
    __shared__ int s_f32, s_nz;
    const int t = threadIdx.x;  // 256
    if (t == 0) { s_f32 = 0; s_nz = 0; }
    __syncthreads();
    int bad = 0;
#pragma unroll 4
    for (int j = 0; j < 64; ++j) {
        unsigned int u = emb16[t * 64 + j];
        if (((u >> 7) & 0xFFu) == 0xFFu) bad = 1;
    }
    int nz = 0;
#pragma unroll
    for (int j = 0; j < 8; ++j)
        if (e32[(t * 8 + j) * 2 + 1] != 0) nz = 1;
    if (bad) atomicOr(&s_f32, 1);
    if (nz) atomicOr(&s_nz, 1);
    __syncthreads();
    const int in_f32 = s_f32;
    const int i64 = s_nz ? 0 : 1;
    if (blockIdx.x == 0 && t == 0) { flags[0] = in_f32; flags[1] = i64; }

    // ---- W pack (blocks 0-2) ----
    const int w = blockIdx.x;
    if (w < 3) {
        const void* Wv = (w == 0) ? w0v : (w == 1 ? w1v : w2v);
        unsigned short* dst = Wb + w * 16384;
        if (in_f32) {
            const float* W = (const float*)Wv;
#pragma unroll
            for (int it = 0; it < 8; ++it) {
                int i = (t + it * 256) * 8;
                float f[8];
                *(u32x4*)&f[0] = *(const u32x4*)(W + i);
                *(u32x4*)&f[4] = *(const u32x4*)(W + i + 4);
                *(short8*)(dst + i) = pack8(f);
            }
        } else {
            const unsigned short* W = (const unsigned short*)Wv;
#pragma unroll
            for (int it = 0; it < 8; ++it) {
                int i = (t + it * 256) * 8;
                *(u32x4*)(dst + i) = *(const u32x4*)(W + i);
            }
        }
    }

    // ---- edge conversion: 2048 edges per block ----
    const int base = blockIdx.x * 2048;
#pragma unroll
    for (int it = 0; it < 8; ++it) {
        int e = base + it * 256 + t;
        if (e < n_edges) {
            int a, b;
            if (i64) { i32x4 ev = __builtin_nontemporal_load((const i32x4*)(e32 + 4 * (size_t)e)); a = ev[0]; b = ev[2]; }
            else     { i32x2 ev = __builtin_nontemporal_load((const i32x2*)(e32 + 2 * (size_t)e)); a = ev[0]; b = ev[1]; }
            i32x2 p; p[0] = a; p[1] = b;
            *(i32x2*)(Ep + 2 * (size_t)e) = p;  // normal store: keep in L2 for edge_kernel
        }
    }
}

// ---------------------------------------------------------------------------
// Phase 1: per-node projections, all three W's in ONE pass over emb.
//   A-side split precision (emb = bf16 hi + bf16 residual, MFMA'd twice)
//   removes the A-side rounding error; planes stored as:
//     SL = round(sigmoid(emb.Wl^T)*255)  u8   (abs err <= 1/510 per gate)
//     SR = round(sigmoid(emb.Wr^T)*255)  u8
//     U  = emb.Wu^T + bias/2             f16  (bias folded; edge adds U'a+U'b)
//   u8 planes are 128 B/node -> exactly ONE cache line per edge row-gather.
//   128x128 tile, 4 waves (2x2), mfma 16x16x32 bf16, B frags from prepacked Wb.
// ---------------------------------------------------------------------------
__global__ __launch_bounds__(256, 2)
void proj_kernel(const void* __restrict__ embv,
                 const unsigned short* __restrict__ Wb,
                 unsigned char* __restrict__ SLp,
                 unsigned char* __restrict__ SRp,
                 unsigned short* __restrict__ Up,
                 const void* __restrict__ biasv,
                 const int* __restrict__ flags, int n_nodes)
{
    const int in_f32 = flags[0];
    const int m0 = blockIdx.x * 128;

    __shared__ unsigned short ldsh[128 * 136];  // A hi plane (bf16)
    __shared__ unsigned short ldsl[128 * 136];  // A lo residual plane (bf16)

    const int tid  = threadIdx.x;
    const int lane = tid & 63;
    const int wave = tid >> 6;
    const int wm   = wave & 1;
    const int wn   = wave >> 1;
    const int l15  = lane & 15;
    const int lgp  = lane >> 4;

    // ---- stage A tile (hi/lo split in f32 case) ----
    if (in_f32) {
        const float* emb = (const float*)embv;
#pragma unroll
        for (int it = 0; it < 8; ++it) {
            int i = tid + it * 256;
            int row = i >> 4, ch = i & 15;
            int g = m0 + row;
            float f[8] = {0.f, 0.f, 0.f, 0.f, 0.f, 0.f, 0.f, 0.f};
            if (g < n_nodes) {
                const float* src = emb + (size_t)g * 128 + ch * 8;
                *(u32x4*)&f[0] = __builtin_nontemporal_load((const u32x4*)src);
                *(u32x4*)&f[4] = __builtin_nontemporal_load((const u32x4*)(src + 4));
            }
            short8 h, l;
#pragma unroll
            for (int j = 0; j < 8; ++j) {
                unsigned int uh = bfrne(f[j]);
                h[j] = (short)uh;
                float r = f[j] - __uint_as_float(uh << 16);
                l[j] = (short)bfrne(r);
            }
            *(short8*)(&ldsh[row * 136 + ch * 8]) = h;
            *(short8*)(&ldsl[row * 136 + ch * 8]) = l;
        }
    } else {
        const unsigned short* emb = (const unsigned short*)embv;
#pragma unroll
        for (int it = 0; it < 4; ++it) {
            int i = tid + it * 256;
            int row = i >> 3, ch = i & 7;
            int g = m0 + row;
            u32x4 v = (u32x4){0u, 0u, 0u, 0u};
            if (g < n_nodes) v = *(const u32x4*)(emb + (size_t)g * 128 + ch * 8);
            *(u32x4*)(&ldsh[row * 136 + ch * 8]) = v;
        }
    }

    __syncthreads();

    // ---- loop over the three projections; A stays resident in LDS ----
#pragma unroll 1
    for (int w = 0; w < 3; ++w) {
        const unsigned short* Wp = Wb + w * 16384;

        // B fragments: B[k=lgp*8+j][n=l15] = W[n][k], prepacked bf16
        short8 bf[4][4];
#pragma unroll
        for (int nj = 0; nj < 4; ++nj) {
            const unsigned short* wrow = Wp + (size_t)(wn * 64 + nj * 16 + l15) * 128 + lgp * 8;
#pragma unroll
            for (int s = 0; s < 4; ++s)
                bf[s][nj] = *(const short8*)(wrow + s * 32);
        }

        f32x4 acc[4][4];
#pragma unroll
        for (int mi = 0; mi < 4; ++mi)
#pragma unroll
            for (int nj = 0; nj < 4; ++nj)
                acc[mi][nj] = (f32x4){0.f, 0.f, 0.f, 0.f};

#pragma unroll
        for (int s = 0; s < 4; ++s) {
            short8 afh[4];
#pragma unroll
            for (int mi = 0; mi < 4; ++mi)
                afh[mi] = *(const short8*)(&ldsh[(wm * 64 + mi * 16 + l15) * 136 + s * 32 + lgp * 8]);
#pragma unroll
            for (int mi = 0; mi < 4; ++mi)
#pragma unroll
                for (int nj = 0; nj < 4; ++nj)
                    acc[mi][nj] = __builtin_amdgcn_mfma_f32_16x16x32_bf16(
                        afh[mi], bf[s][nj], acc[mi][nj], 0, 0, 0);
            if (in_f32) {
                short8 afl[4];
#pragma unroll
                for (int mi = 0; mi < 4; ++mi)
                    afl[mi] = *(const short8*)(&ldsl[(wm * 64 + mi * 16 + l15) * 136 + s * 32 + lgp * 8]);
#pragma unroll
                for (int mi = 0; mi < 4; ++mi)
#pragma unroll
                    for (int nj = 0; nj < 4; ++nj)
                        acc[mi][nj] = __builtin_amdgcn_mfma_f32_16x16x32_bf16(
                            afl[mi], bf[s][nj], acc[mi][nj], 0, 0, 0);
            }
        }

        // Epilogue. C/D: col = lane&15, row = (lane>>4)*4 + reg.
        const bool odd = (lane & 1);
        if (w < 2) {
            // Gate planes -> u8. Two shuffle stages merge 4 cols into one
            // 4-byte store per lane per (mi,nj).
            unsigned char* out8 = (w == 0) ? SLp : SRp;
#pragma unroll
            for (int mi = 0; mi < 4; ++mi) {
                int nodeBase = m0 + wm * 64 + mi * 16 + lgp * 4;
#pragma unroll
                for (int nj = 0; nj < 4; ++nj) {
                    unsigned int q0 = (unsigned int)(sigmoidf_fast(acc[mi][nj][0]) * 255.f + 0.5f);
                    unsigned int q1 = (unsigned int)(sigmoidf_fast(acc[mi][nj][1]) * 255.f + 0.5f);
                    unsigned int q2 = (unsigned int)(sigmoidf_fast(acc[mi][nj][2]) * 255.f + 0.5f);
                    unsigned int q3 = (unsigned int)(sigmoidf_fast(acc[mi][nj][3]) * 255.f + 0.5f);
                    unsigned int p0 = (unsigned int)__shfl_xor((int)q0, 1);
                    unsigned int p1 = (unsigned int)__shfl_xor((int)q1, 1);
                    unsigned int p2 = (unsigned int)__shfl_xor((int)q2, 1);
                    unsigned int p3 = (unsigned int)__shfl_xor((int)q3, 1);
                    // stage 1: 2 cols x u8 in a 16-bit half; rows (0,1) even / (2,3) odd
                    unsigned int hA, hB;
                    if (!odd) { hA = q0 | (p0 << 8); hB = q1 | (p1 << 8); }
                    else      { hA = p2 | (q2 << 8); hB = p3 | (q3 << 8); }
                    // stage 2: merge col-pairs across lane^2 -> 4 cols
                    unsigned int mA = (unsigned int)__shfl_xor((int)hA, 2);
                    unsigned int mB = (unsigned int)__shfl_xor((int)hB, 2);
                    unsigned int wordA = (l15 & 2) ? (mA | (hA << 16)) : (hA | (mA << 16));
                    unsigned int wordB = (l15 & 2) ? (mB | (hB << 16)) : (hB | (mB << 16));
                    int sel = l15 & 3;
                    int r = (sel & 1) * 2 + (sel >> 1);       // 0,2,1,3
                    unsigned int word = (sel >> 1) ? wordB : wordA;
                    int node = nodeBase + r;
                    int colB = wn * 64 + nj * 16 + (l15 & ~3);
                    if (node < n_nodes)
                        *(unsigned int*)(out8 + (size_t)node * 128 + colB) = word;
                }
            }
        } else {
            // U plane -> f16, bias/2 folded in before rounding.
            const float* bias_f = (const float*)biasv;
            const unsigned short* bias_h = (const unsigned short*)biasv;
#pragma unroll
            for (int mi = 0; mi < 4; ++mi) {
                int nodeBase = m0 + wm * 64 + mi * 16 + lgp * 4;
#pragma unroll
                for (int nj = 0; nj < 4; ++nj) {
                    int col = wn * 64 + nj * 16 + l15;
                    float bv = 0.5f * (in_f32 ? bias_f[col]
                                              : __uint_as_float(((unsigned int)bias_h[col]) << 16));
                    float v0 = acc[mi][nj][0] + bv;
                    float v1 = acc[mi][nj][1] + bv;
                    float v2 = acc[mi][nj][2] + bv;
                    float v3 = acc[mi][nj][3] + bv;
                    float p0 = __shfl_xor(v0, 1), p1 = __shfl_xor(v1, 1);
                    float p2 = __shfl_xor(v2, 1), p3 = __shfl_xor(v3, 1);
                    unsigned int pkA, pkB; int rA, rB;
                    if (!odd) { pkA = packh2(v0, p0); rA = 0; pkB = packh2(v1, p1); rB = 1; }
                    else      { pkA = packh2(p2, v2); rA = 2; pkB = packh2(p3, v3); rB = 3; }
                    int colE = wn * 64 + nj * 16 + (l15 & ~1);
                    int na = nodeBase + rA, nb = nodeBase + rB;
                    if (na < n_nodes) *(unsigned int*)(Up + (size_t)na * 128 + colE) = pkA;
                    if (nb < n_nodes) *(unsigned int*)(Up + (size_t)nb * 128 + colE) = pkB;
                }
            }
        }
    }
}

// ---------------------------------------------------------------------------
// Phase 2: per-edge combine. 512 threads/block, 16 threads/edge, 8 ch each.
//   out[e] = ((SL8[a]+SR8[b])/255) * tanh(U'[a] + U'[b])
// Gather: 768 B/edge (6 cache lines). Indices from prepacked int32 pairs
// (branchless, 8 B/edge). Output stores nontemporal: 307 MB streaming write
// must not evict the 51.2 MB plane working set from L2.
// ---------------------------------------------------------------------------
__global__ __launch_bounds__(512)
void edge_kernel(const int* __restrict__ Ep,
                 const unsigned char* __restrict__ SL,
                 const unsigned char* __restrict__ SR,
                 const unsigned short* __restrict__ U,
                 void* __restrict__ outv,
                 const int* __restrict__ flags, int n_edges)
{
    const int in_f32 = flags[0];
    const int tid = threadIdx.x;
    const int e = blockIdx.x * 32 + (tid >> 4);
    if (e >= n_edges) return;
    const int c = (tid & 15) * 8;

    i32x2 ev = __builtin_nontemporal_load((const i32x2*)(Ep + 2 * (size_t)e));
    const int a = ev[0], b = ev[1];

    u32x2 qla = *(const u32x2*)(SL + (size_t)a * 128 + c);
    u32x2 qrb = *(const u32x2*)(SR + (size_t)b * 128 + c);
    float uaf[8], ubf[8];
    unpackh8(*(const u32x4*)(U + (size_t)a * 128 + c), uaf);
    unpackh8(*(const u32x4*)(U + (size_t)b * 128 + c), ubf);

    const float inv255 = 1.f / 255.f;
    float o[8];
#pragma unroll
    for (int j = 0; j < 4; ++j) {
        float s = (float)(((qla[0] >> (8 * j)) & 255u) + ((qrb[0] >> (8 * j)) & 255u)) * inv255;
        o[j] = s * tanhf_fast(uaf[j] + ubf[j]);
    }
#pragma unroll
    for (int j = 0; j < 4; ++j) {
        float s = (float)(((qla[1] >> (8 * j)) & 255u) + ((qrb[1] >> (8 * j)) & 255u)) * inv255;
        o[4 + j] = s * tanhf_fast(uaf[4 + j] + ubf[4 + j]);
    }

    if (in_f32) {
        float* op = (float*)outv + (size_t)e * 128 + c;
        __builtin_nontemporal_store(*(const u32x4*)&o[0], (u32x4*)op);
        __builtin_nontemporal_store(*(const u32x4*)&o[4], (u32x4*)(op + 4));
    } else {
        unsigned int res[4];
#pragma unroll
        for (int j = 0; j < 4; ++j) res[j] = packbf2(o[2 * j], o[2 * j + 1]);
        __builtin_nontemporal_store(*(const u32x4*)res,
                                    (u32x4*)((unsigned short*)outv + (size_t)e * 128 + c));
    }
}

extern "C" void kernel_launch(void* const* d_in, const int* in_sizes, int n_in,
                              void* d_out, int out_size, void* d_ws, size_t ws_size,
                              hipStream_t stream)
{
    const void* emb   = d_in[0];
    const int*  edges = (const int*)d_in[1];
    const void* Wl    = d_in[2];
    const void* Wr    = d_in[3];
    const void* Wu    = d_in[4];
    const void* bias  = d_in[5];

    const int n_nodes = in_sizes[0] / 128;
    const int n_edges = in_sizes[1] / 2;

    int* flags = (int*)d_ws;
    unsigned short* Wb = (unsigned short*)((char*)d_ws + 256);     // 3 x 128x128 bf16 = 96KB
    int* Ep = (int*)(Wb + 3 * 16384);                              // packed (a,b) i32, 4.8MB
    unsigned char* SLp = (unsigned char*)(Ep + 2 * (size_t)n_edges);      // u8 plane, 12.8MB
    unsigned char* SRp = SLp + (size_t)n_nodes * 128;                     // u8 plane, 12.8MB
    unsigned short* Up = (unsigned short*)(SRp + (size_t)n_nodes * 128);  // f16, 25.6MB

    int gprep = (n_edges + 2047) / 2048;
    if (gprep < 3) gprep = 3;
    prep_kernel<<<gprep, 256, 0, stream>>>(Wl, Wr, Wu, Wb,
                                           (const unsigned short*)emb, edges, Ep,
                                           flags, n_edges);

    dim3 g1((n_nodes + 127) / 128);
    proj_kernel<<<g1, 256, 0, stream>>>(emb, Wb, SLp, SRp, Up, bias, flags, n_nodes);

    int g2 = (n_edges + 31) / 32;
    edge_kernel<<<g2, 512, 0, stream>>>(Ep, SLp, SRp, Up, d_out, flags, n_edges);
}

// Round 5
// 470.497 us; speedup vs baseline: 1.0134x; 1.0134x over previous
//
#include <hip/hip_runtime.h>
#include <hip/hip_bf16.h>
#include <hip/hip_fp16.h>

typedef __attribute__((ext_vector_type(8))) short short8;
typedef __attribute__((ext_vector_type(4))) float f32x4;
typedef __attribute__((ext_vector_type(4))) unsigned int u32x4;
typedef __attribute__((ext_vector_type(2))) unsigned int u32x2;
typedef __attribute__((ext_vector_type(4))) int i32x4;
typedef __attribute__((ext_vector_type(2))) int i32x2;

// ---------------- bf16 helpers ----------------
__device__ __forceinline__ float bflo(unsigned int u) { return __uint_as_float(u << 16); }
__device__ __forceinline__ float bfhi(unsigned int u) { return __uint_as_float(u & 0xffff0000u); }
__device__ __forceinline__ unsigned int bfrne(float f) {
    unsigned int u = __float_as_uint(f);
    return (u + 0x7fffu + ((u >> 16) & 1u)) >> 16;
}
__device__ __forceinline__ unsigned int packbf2(float lo, float hi) {
    return (bfrne(lo) & 0xffffu) | (bfrne(hi) << 16);
}
__device__ __forceinline__ short8 pack8(const float* f) {
    short8 r;
#pragma unroll
    for (int i = 0; i < 8; i += 2) {
        unsigned int p = packbf2(f[i], f[i + 1]);
        r[i] = (short)(p & 0xffffu);
        r[i + 1] = (short)(p >> 16);
    }
    return r;
}

// ---------------- f16 helpers ----------------
__device__ __forceinline__ unsigned int packh2(float lo, float hi) {
    unsigned int a = __half_as_ushort(__float2half_rn(lo));
    unsigned int b = __half_as_ushort(__float2half_rn(hi));
    return a | (b << 16);
}
__device__ __forceinline__ void unpackh8(u32x4 v, float* f) {
#pragma unroll
    for (int j = 0; j < 4; ++j) {
        f[2 * j]     = __half2float(__ushort_as_half((unsigned short)(v[j] & 0xffffu)));
        f[2 * j + 1] = __half2float(__ushort_as_half((unsigned short)(v[j] >> 16)));
    }
}

// ---------------- fast math ----------------
__device__ __forceinline__ float fast_rcp(float x) { return __builtin_amdgcn_rcpf(x); }
__device__ __forceinline__ float sigmoidf_fast(float x) { return fast_rcp(1.0f + __expf(-x)); }
__device__ __forceinline__ float tanhf_fast(float x) {
    float e = __expf(2.0f * x);
    return 1.0f - 2.0f * fast_rcp(e + 1.0f);
}

// ---------------------------------------------------------------------------
// Prep: sniff dtypes locally (each block scans 32KB of emb + 4KB of edges) AND
// pack the three 128x128 W matrices to bf16. Block 0 publishes flags for the
// downstream kernels (same-stream ordering guarantees visibility).
//   flags[0]=1 iff emb is f32-backed (bf16 of N(0,1) never has exp 0xFF).
//   flags[1]=1 iff edges are int64 (hi-words of indices <100000 all zero).
// ---------------------------------------------------------------------------
__global__ __launch_bounds__(256)
void prep_kernel(const void* __restrict__ w0v, const void* __restrict__ w1v,
                 const void* __restrict__ w2v,
                 unsigned short* __restrict__ Wb,
                 const unsigned short* __restrict__ emb16,
                 const int* __restrict__ e32,
                 int* __restrict__ flags)
{
    __shared__ int s_f32, s_nz;
    const int t = threadIdx.x;  // 256
    if (t == 0) { s_f32 = 0; s_nz = 0; }
    __syncthreads();
    int bad = 0;
#pragma unroll 4
    for (int j = 0; j < 64; ++j) {
        unsigned int u = emb16[t * 64 + j];
        if (((u >> 7) & 0xFFu) == 0xFFu) bad = 1;
    }
    int nz = 0;
#pragma unroll
    for (int j = 0; j < 8; ++j)
        if (e32[(t * 8 + j) * 2 + 1] != 0) nz = 1;
    if (bad) atomicOr(&s_f32, 1);
    if (nz) atomicOr(&s_nz, 1);
    __syncthreads();
    const int in_f32 = s_f32;
    if (blockIdx.x == 0 && t == 0) { flags[0] = in_f32; flags[1] = s_nz ? 0 : 1; }

    const int w = blockIdx.x;
    const void* Wv = (w == 0) ? w0v : (w == 1 ? w1v : w2v);
    unsigned short* dst = Wb + w * 16384;
    if (in_f32) {
        const float* W = (const float*)Wv;
#pragma unroll
        for (int it = 0; it < 8; ++it) {
            int i = (t + it * 256) * 8;
            float f[8];
            *(u32x4*)&f[0] = *(const u32x4*)(W + i);
            *(u32x4*)&f[4] = *(const u32x4*)(W + i + 4);
            *(short8*)(dst + i) = pack8(f);
        }
    } else {
        const unsigned short* W = (const unsigned short*)Wv;
#pragma unroll
        for (int it = 0; it < 8; ++it) {
            int i = (t + it * 256) * 8;
            *(u32x4*)(dst + i) = *(const u32x4*)(W + i);
        }
    }
}

// ---------------------------------------------------------------------------
// Phase 1: per-node projections, all three W's in ONE pass over emb.
//   A-side split precision (emb = bf16 hi + bf16 residual, MFMA'd twice)
//   removes the A-side rounding error; planes stored as:
//     SL = round(sigmoid(emb.Wl^T)*255)  u8   (abs err <= 1/510 per gate)
//     SR = round(sigmoid(emb.Wr^T)*255)  u8
//     U  = emb.Wu^T + bias/2             f16  (bias folded; edge adds U'a+U'b)
//   u8 planes are 128 B/node -> exactly ONE cache line per edge row-gather.
//   128x128 tile, 4 waves (2x2), mfma 16x16x32 bf16, B frags from prepacked Wb.
// ---------------------------------------------------------------------------
__global__ __launch_bounds__(256, 2)
void proj_kernel(const void* __restrict__ embv,
                 const unsigned short* __restrict__ Wb,
                 unsigned char* __restrict__ SLp,
                 unsigned char* __restrict__ SRp,
                 unsigned short* __restrict__ Up,
                 const void* __restrict__ biasv,
                 const int* __restrict__ flags, int n_nodes)
{
    const int in_f32 = flags[0];
    const int m0 = blockIdx.x * 128;

    __shared__ unsigned short ldsh[128 * 136];  // A hi plane (bf16)
    __shared__ unsigned short ldsl[128 * 136];  // A lo residual plane (bf16)

    const int tid  = threadIdx.x;
    const int lane = tid & 63;
    const int wave = tid >> 6;
    const int wm   = wave & 1;
    const int wn   = wave >> 1;
    const int l15  = lane & 15;
    const int lgp  = lane >> 4;

    // ---- stage A tile (hi/lo split in f32 case) ----
    if (in_f32) {
        const float* emb = (const float*)embv;
#pragma unroll
        for (int it = 0; it < 8; ++it) {
            int i = tid + it * 256;
            int row = i >> 4, ch = i & 15;
            int g = m0 + row;
            float f[8] = {0.f, 0.f, 0.f, 0.f, 0.f, 0.f, 0.f, 0.f};
            if (g < n_nodes) {
                const float* src = emb + (size_t)g * 128 + ch * 8;
                *(u32x4*)&f[0] = __builtin_nontemporal_load((const u32x4*)src);
                *(u32x4*)&f[4] = __builtin_nontemporal_load((const u32x4*)(src + 4));
            }
            short8 h, l;
#pragma unroll
            for (int j = 0; j < 8; ++j) {
                unsigned int uh = bfrne(f[j]);
                h[j] = (short)uh;
                float r = f[j] - __uint_as_float(uh << 16);
                l[j] = (short)bfrne(r);
            }
            *(short8*)(&ldsh[row * 136 + ch * 8]) = h;
            *(short8*)(&ldsl[row * 136 + ch * 8]) = l;
        }
    } else {
        const unsigned short* emb = (const unsigned short*)embv;
#pragma unroll
        for (int it = 0; it < 4; ++it) {
            int i = tid + it * 256;
            int row = i >> 3, ch = i & 7;
            int g = m0 + row;
            u32x4 v = (u32x4){0u, 0u, 0u, 0u};
            if (g < n_nodes) v = *(const u32x4*)(emb + (size_t)g * 128 + ch * 8);
            *(u32x4*)(&ldsh[row * 136 + ch * 8]) = v;
        }
    }

    __syncthreads();

    // ---- loop over the three projections; A stays resident in LDS ----
#pragma unroll 1
    for (int w = 0; w < 3; ++w) {
        const unsigned short* Wp = Wb + w * 16384;

        // B fragments: B[k=lgp*8+j][n=l15] = W[n][k], prepacked bf16
        short8 bf[4][4];
#pragma unroll
        for (int nj = 0; nj < 4; ++nj) {
            const unsigned short* wrow = Wp + (size_t)(wn * 64 + nj * 16 + l15) * 128 + lgp * 8;
#pragma unroll
            for (int s = 0; s < 4; ++s)
                bf[s][nj] = *(const short8*)(wrow + s * 32);
        }

        f32x4 acc[4][4];
#pragma unroll
        for (int mi = 0; mi < 4; ++mi)
#pragma unroll
            for (int nj = 0; nj < 4; ++nj)
                acc[mi][nj] = (f32x4){0.f, 0.f, 0.f, 0.f};

#pragma unroll
        for (int s = 0; s < 4; ++s) {
            short8 afh[4];
#pragma unroll
            for (int mi = 0; mi < 4; ++mi)
                afh[mi] = *(const short8*)(&ldsh[(wm * 64 + mi * 16 + l15) * 136 + s * 32 + lgp * 8]);
#pragma unroll
            for (int mi = 0; mi < 4; ++mi)
#pragma unroll
                for (int nj = 0; nj < 4; ++nj)
                    acc[mi][nj] = __builtin_amdgcn_mfma_f32_16x16x32_bf16(
                        afh[mi], bf[s][nj], acc[mi][nj], 0, 0, 0);
            if (in_f32) {
                short8 afl[4];
#pragma unroll
                for (int mi = 0; mi < 4; ++mi)
                    afl[mi] = *(const short8*)(&ldsl[(wm * 64 + mi * 16 + l15) * 136 + s * 32 + lgp * 8]);
#pragma unroll
                for (int mi = 0; mi < 4; ++mi)
#pragma unroll
                    for (int nj = 0; nj < 4; ++nj)
                        acc[mi][nj] = __builtin_amdgcn_mfma_f32_16x16x32_bf16(
                            afl[mi], bf[s][nj], acc[mi][nj], 0, 0, 0);
            }
        }

        // Epilogue. C/D: col = lane&15, row = (lane>>4)*4 + reg.
        const bool odd = (lane & 1);
        if (w < 2) {
            // Gate planes -> u8. Two shuffle stages merge 4 cols into one
            // 4-byte store per lane per (mi,nj).
            unsigned char* out8 = (w == 0) ? SLp : SRp;
#pragma unroll
            for (int mi = 0; mi < 4; ++mi) {
                int nodeBase = m0 + wm * 64 + mi * 16 + lgp * 4;
#pragma unroll
                for (int nj = 0; nj < 4; ++nj) {
                    unsigned int q0 = (unsigned int)(sigmoidf_fast(acc[mi][nj][0]) * 255.f + 0.5f);
                    unsigned int q1 = (unsigned int)(sigmoidf_fast(acc[mi][nj][1]) * 255.f + 0.5f);
                    unsigned int q2 = (unsigned int)(sigmoidf_fast(acc[mi][nj][2]) * 255.f + 0.5f);
                    unsigned int q3 = (unsigned int)(sigmoidf_fast(acc[mi][nj][3]) * 255.f + 0.5f);
                    unsigned int p0 = (unsigned int)__shfl_xor((int)q0, 1);
                    unsigned int p1 = (unsigned int)__shfl_xor((int)q1, 1);
                    unsigned int p2 = (unsigned int)__shfl_xor((int)q2, 1);
                    unsigned int p3 = (unsigned int)__shfl_xor((int)q3, 1);
                    // stage 1: 2 cols x u8 in a 16-bit half; rows (0,1) even / (2,3) odd
                    unsigned int hA, hB;
                    if (!odd) { hA = q0 | (p0 << 8); hB = q1 | (p1 << 8); }
                    else      { hA = p2 | (q2 << 8); hB = p3 | (q3 << 8); }
                    // stage 2: merge col-pairs across lane^2 -> 4 cols
                    unsigned int mA = (unsigned int)__shfl_xor((int)hA, 2);
                    unsigned int mB = (unsigned int)__shfl_xor((int)hB, 2);
                    unsigned int wordA = (l15 & 2) ? (mA | (hA << 16)) : (hA | (mA << 16));
                    unsigned int wordB = (l15 & 2) ? (mB | (hB << 16)) : (hB | (mB << 16));
                    int sel = l15 & 3;
                    int r = (sel & 1) * 2 + (sel >> 1);       // 0,2,1,3
                    unsigned int word = (sel >> 1) ? wordB : wordA;
                    int node = nodeBase + r;
                    int colB = wn * 64 + nj * 16 + (l15 & ~3);
                    if (node < n_nodes)
                        *(unsigned int*)(out8 + (size_t)node * 128 + colB) = word;
                }
            }
        } else {
            // U plane -> f16, bias/2 folded in before rounding.
            const float* bias_f = (const float*)biasv;
            const unsigned short* bias_h = (const unsigned short*)biasv;
#pragma unroll
            for (int mi = 0; mi < 4; ++mi) {
                int nodeBase = m0 + wm * 64 + mi * 16 + lgp * 4;
#pragma unroll
                for (int nj = 0; nj < 4; ++nj) {
                    int col = wn * 64 + nj * 16 + l15;
                    float bv = 0.5f * (in_f32 ? bias_f[col]
                                              : __uint_as_float(((unsigned int)bias_h[col]) << 16));
                    float v0 = acc[mi][nj][0] + bv;
                    float v1 = acc[mi][nj][1] + bv;
                    float v2 = acc[mi][nj][2] + bv;
                    float v3 = acc[mi][nj][3] + bv;
                    float p0 = __shfl_xor(v0, 1), p1 = __shfl_xor(v1, 1);
                    float p2 = __shfl_xor(v2, 1), p3 = __shfl_xor(v3, 1);
                    unsigned int pkA, pkB; int rA, rB;
                    if (!odd) { pkA = packh2(v0, p0); rA = 0; pkB = packh2(v1, p1); rB = 1; }
                    else      { pkA = packh2(p2, v2); rA = 2; pkB = packh2(p3, v3); rB = 3; }
                    int colE = wn * 64 + nj * 16 + (l15 & ~1);
                    int na = nodeBase + rA, nb = nodeBase + rB;
                    if (na < n_nodes) *(unsigned int*)(Up + (size_t)na * 128 + colE) = pkA;
                    if (nb < n_nodes) *(unsigned int*)(Up + (size_t)nb * 128 + colE) = pkB;
                }
            }
        }
    }
}

// ---------------------------------------------------------------------------
// Phase 2: per-edge combine. 16 threads/edge, 8 channels each.
//   out[e] = ((SL8[a]+SR8[b])/255) * tanh(U'[a] + U'[b])
// Gather: 768 B/edge (6 cache lines: 1+1 u8 gate rows, 2+2 f16 U rows).
// Output stores are nontemporal: 307 MB streaming write must not evict the
// 51.2 MB plane working set from L2.
// ---------------------------------------------------------------------------
__global__ __launch_bounds__(256)
void edge_kernel(const int* __restrict__ e32,
                 const unsigned char* __restrict__ SL,
                 const unsigned char* __restrict__ SR,
                 const unsigned short* __restrict__ U,
                 void* __restrict__ outv,
                 const int* __restrict__ flags, int n_edges)
{
    const int in_f32 = flags[0];
    const int i64    = flags[1];
    const int tid = threadIdx.x;
    const int e = blockIdx.x * 16 + (tid >> 4);
    if (e >= n_edges) return;
    const int c = (tid & 15) * 8;

    int a, b;
    if (i64) { i32x4 ev = __builtin_nontemporal_load((const i32x4*)(e32 + 4 * (size_t)e)); a = ev[0]; b = ev[2]; }
    else     { i32x2 ev = __builtin_nontemporal_load((const i32x2*)(e32 + 2 * (size_t)e)); a = ev[0]; b = ev[1]; }

    u32x2 qla = *(const u32x2*)(SL + (size_t)a * 128 + c);
    u32x2 qrb = *(const u32x2*)(SR + (size_t)b * 128 + c);
    float uaf[8], ubf[8];
    unpackh8(*(const u32x4*)(U + (size_t)a * 128 + c), uaf);
    unpackh8(*(const u32x4*)(U + (size_t)b * 128 + c), ubf);

    const float inv255 = 1.f / 255.f;
    float o[8];
#pragma unroll
    for (int j = 0; j < 4; ++j) {
        float s = (float)(((qla[0] >> (8 * j)) & 255u) + ((qrb[0] >> (8 * j)) & 255u)) * inv255;
        o[j] = s * tanhf_fast(uaf[j] + ubf[j]);
    }
#pragma unroll
    for (int j = 0; j < 4; ++j) {
        float s = (float)(((qla[1] >> (8 * j)) & 255u) + ((qrb[1] >> (8 * j)) & 255u)) * inv255;
        o[4 + j] = s * tanhf_fast(uaf[4 + j] + ubf[4 + j]);
    }

    if (in_f32) {
        float* op = (float*)outv + (size_t)e * 128 + c;
        __builtin_nontemporal_store(*(const u32x4*)&o[0], (u32x4*)op);
        __builtin_nontemporal_store(*(const u32x4*)&o[4], (u32x4*)(op + 4));
    } else {
        unsigned int res[4];
#pragma unroll
        for (int j = 0; j < 4; ++j) res[j] = packbf2(o[2 * j], o[2 * j + 1]);
        __builtin_nontemporal_store(*(const u32x4*)res,
                                    (u32x4*)((unsigned short*)outv + (size_t)e * 128 + c));
    }
}

extern "C" void kernel_launch(void* const* d_in, const int* in_sizes, int n_in,
                              void* d_out, int out_size, void* d_ws, size_t ws_size,
                              hipStream_t stream)
{
    const void* emb   = d_in[0];
    const int*  edges = (const int*)d_in[1];
    const void* Wl    = d_in[2];
    const void* Wr    = d_in[3];
    const void* Wu    = d_in[4];
    const void* bias  = d_in[5];

    const int n_nodes = in_sizes[0] / 128;
    const int n_edges = in_sizes[1] / 2;

    int* flags = (int*)d_ws;
    unsigned short* Wb = (unsigned short*)((char*)d_ws + 256);     // 3 x 128x128 bf16 = 96KB
    unsigned char* SLp = (unsigned char*)(Wb + 3 * 16384);         // u8 plane, 12.8MB
    unsigned char* SRp = SLp + (size_t)n_nodes * 128;              // u8 plane, 12.8MB
    unsigned short* Up = (unsigned short*)(SRp + (size_t)n_nodes * 128);  // f16, 25.6MB

    prep_kernel<<<3, 256, 0, stream>>>(Wl, Wr, Wu, Wb,
                                       (const unsigned short*)emb, edges, flags);

    dim3 g1((n_nodes + 127) / 128);
    proj_kernel<<<g1, 256, 0, stream>>>(emb, Wb, SLp, SRp, Up, bias, flags, n_nodes);

    int g2 = (n_edges + 15) / 16;
    edge_kernel<<<g2, 256, 0, stream>>>(edges, SLp, SRp, Up, d_out, flags, n_edges);
}